// Round 7
// baseline (422.154 us; speedup 1.0000x reference)
//
#include <hip/hip_runtime.h>
#include <stdint.h>

#define E4M3_MAX 448.0f

typedef float f32x4 __attribute__((ext_vector_type(4)));
typedef int   i32x4 __attribute__((ext_vector_type(4)));
typedef int   i32x8 __attribute__((ext_vector_type(8)));

// ---------------------------------------------------------------------------
// async global -> LDS, 16 bytes per lane. LDS dest stays LINEAR (HW
// constraint); T2 swizzle applied by pre-swizzling the GLOBAL source column
// and swizzling the LDS READ offset with the same involution (rule #21).
// ---------------------------------------------------------------------------
__device__ __forceinline__ void gload_lds16(const void* g, void* l) {
    __builtin_amdgcn_global_load_lds(
        (__attribute__((address_space(1))) void*)(void*)g,
        (__attribute__((address_space(3))) void*)l,
        16, 0, 0);
}

__device__ __forceinline__ uint32_t quant4(float a, float b, float c, float d) {
    a = fminf(fmaxf(a, -E4M3_MAX), E4M3_MAX);
    b = fminf(fmaxf(b, -E4M3_MAX), E4M3_MAX);
    c = fminf(fmaxf(c, -E4M3_MAX), E4M3_MAX);
    d = fminf(fmaxf(d, -E4M3_MAX), E4M3_MAX);
    int q = 0;
    q = __builtin_amdgcn_cvt_pk_fp8_f32(a, b, q, false);
    q = __builtin_amdgcn_cvt_pk_fp8_f32(c, d, q, true);
    return (uint32_t)q;
}

__global__ void quant_x_kernel(const float* __restrict__ x,
                               const float* __restrict__ scale_p,
                               uint4* __restrict__ xq, int n16) {
    const float inv = 1.0f / scale_p[0];
    const int stride = gridDim.x * blockDim.x;
    for (int i = blockIdx.x * blockDim.x + threadIdx.x; i < n16; i += stride) {
        const float4* p = (const float4*)x + (size_t)i * 4;
        float4 v0 = p[0], v1 = p[1], v2 = p[2], v3 = p[3];
        uint4 q;
        q.x = quant4(v0.x * inv, v0.y * inv, v0.z * inv, v0.w * inv);
        q.y = quant4(v1.x * inv, v1.y * inv, v1.z * inv, v1.w * inv);
        q.z = quant4(v2.x * inv, v2.y * inv, v2.z * inv, v2.w * inv);
        q.w = quant4(v3.x * inv, v3.y * inv, v3.z * inv, v3.w * inv);
        xq[i] = q;
    }
}

// ---------------------------------------------------------------------------
// quantize w into MFMA-FRAGMENT-SHUFFLED layout so the GEMM can load B
// fragments directly global->register with perfectly coalesced dwordx4.
// Element (n, k):  nf=n>>4, r=n&15, kt=k>>7, kg=(k>>5)&3, koff=k&31
//   dst_byte = ((nf*nkt + kt)*64 + kg*16 + r)*32 + koff
// i.e. per (nf, kt) block of 2048 B, lane l = kg*16+r holds its 32 k-bytes
// contiguously -- exactly the mfma_scale_16x16x128 B-operand layout.
// Each thread quantizes one full 32-byte lane chunk (32 consecutive k of
// one row); lanes cover consecutive rows -> 512B-contiguous stores.
// ---------------------------------------------------------------------------
__global__ void quant_w_kernel(const float* __restrict__ w,
                               const float* __restrict__ wsc,
                               uint8_t* __restrict__ wq,
                               int Nrows, int K, int chunkRows) {
    const int nkt = K >> 7;
    const int n32 = Nrows * (K >> 5);
    const int stride = gridDim.x * blockDim.x;
    for (int i = blockIdx.x * blockDim.x + threadIdx.x; i < n32; i += stride) {
        const int n  = i % Nrows;
        const int k0 = (i / Nrows) << 5;
        const float inv = 1.0f / wsc[n / chunkRows];
        const float4* p = (const float4*)(w + (size_t)n * K + k0);
        uint4 qa, qb;
        {
            float4 v0 = p[0], v1 = p[1], v2 = p[2], v3 = p[3];
            qa.x = quant4(v0.x * inv, v0.y * inv, v0.z * inv, v0.w * inv);
            qa.y = quant4(v1.x * inv, v1.y * inv, v1.z * inv, v1.w * inv);
            qa.z = quant4(v2.x * inv, v2.y * inv, v2.z * inv, v2.w * inv);
            qa.w = quant4(v3.x * inv, v3.y * inv, v3.z * inv, v3.w * inv);
        }
        {
            float4 v0 = p[4], v1 = p[5], v2 = p[6], v3 = p[7];
            qb.x = quant4(v0.x * inv, v0.y * inv, v0.z * inv, v0.w * inv);
            qb.y = quant4(v1.x * inv, v1.y * inv, v1.z * inv, v1.w * inv);
            qb.z = quant4(v2.x * inv, v2.y * inv, v2.z * inv, v2.w * inv);
            qb.w = quant4(v3.x * inv, v3.y * inv, v3.z * inv, v3.w * inv);
        }
        const int kt = k0 >> 7, kg = (k0 >> 5) & 3, r = n & 15, nf = n >> 4;
        uint8_t* dst = wq + (((size_t)nf * nkt + kt) * 64 + kg * 16 + r) * 32;
        *(uint4*)dst = qa;
        *(uint4*)(dst + 16) = qb;
    }
}

__device__ __forceinline__ i32x8 read_frag(const uint8_t* base, int o0, int o1) {
    i32x4 lo = *(const i32x4*)(base + o0);
    i32x4 hi = *(const i32x4*)(base + o1);
    return __builtin_shufflevector(lo, hi, 0, 1, 2, 3, 4, 5, 6, 7);
}

#define MFMA_MX(a, b, c) \
    __builtin_amdgcn_mfma_scale_f32_16x16x128_f8f6f4( \
        (a), (b), (c), 0, 0, 0, 0x7F7F7F7F, 0, 0x7F7F7F7F)

#define WAIT_LGKM(n)                                            \
    do {                                                        \
        asm volatile("s_waitcnt lgkmcnt(" #n ")" ::: "memory"); \
        __builtin_amdgcn_sched_barrier(0);                      \
    } while (0)

// ---------------------------------------------------------------------------
// fp8-MX GEMM, 256x256 tile, 8 waves (2Mx4N), wave-tile 128x64.
// Round-7: B never touches LDS -- loaded global->register from the
// fragment-shuffled wq (L2/L3-resident, coalesced dwordx4). A stays in
// double-buffered LDS (64 KB total). Counted-lgkmcnt A pipeline as round 6.
// Per iter t:
//   top barrier (A tile t staged; buf[cur^1] free)
//   issue B(t) 8 dwordx4 -> regs; issue A frags 0..3 (8 b128);
//   issue stage(t+1) (4 gload_lds)
//   vmcnt(4) [B done, stage in flight] ; lgkm pipeline g0..g3 as round 6
//   vmcnt(0) [stage done, ~3 MFMA groups of slack] ; s_barrier
// ---------------------------------------------------------------------------
#define BM 256
#define BN 256
#define BKB 128

__global__ __launch_bounds__(512, 2) void gemm_fp8_kernel(
    const uint8_t* __restrict__ Aq, const uint8_t* __restrict__ Bq,
    const float* __restrict__ bias, const float* __restrict__ isp,
    const float* __restrict__ wsc, float* __restrict__ out,
    int M, int N, int K, int ocPerChunk) {
    __shared__ __align__(16) uint8_t As[2][BM * BKB];   // A only, 2 x 32 KB

    const int tid  = threadIdx.x;
    const int lane = tid & 63;
    const int wid  = tid >> 6;   // 0..7
    const int wm   = wid >> 2;   // 0..1  (M half)
    const int wn   = wid & 3;    // 0..3  (N quarter)

    // T1 XCD swizzle, by-inner chunking: each XCD gets a band of
    // (nby/8) by-rows; consecutive blocks on an XCD share bx -> the XCD's
    // 32 concurrent CUs work on ~4 B-panels (4 MB, L2-fit).
    const int nbx   = N / BN;
    const int nby   = M / BM;
    const int chunk = nby >> 3;            // by-rows per XCD
    const int xcd   = blockIdx.x & 7;
    const int local = blockIdx.x >> 3;
    const int bx    = local / chunk;
    const int by    = xcd * chunk + (local % chunk);
    const int m0    = by * BM;
    const int n0    = bx * BN;

    const int lr   = lane & 15;
    const int sw   = (lr & 7) << 4;
    const int off0 = ((lane >> 4) * 32) ^ sw;
    const int off1 = off0 ^ 16;

    f32x4 acc[8][4] = {};

    const int nkt = K / BKB;

    // B fragment base: frag ni of wave wn at tile t lives at
    // bbase + (ni*nkt + t)*2048, lane-contiguous 32 B.
    const uint8_t* bbase =
        Bq + ((size_t)((n0 >> 4) + wn * 4) * nkt) * 2048 + lane * 32;

    // stage A K-tile (k-offset kt) into buffer b: 4 x gload_lds16 per thread
    auto stage = [&](int b, int kt) {
#pragma unroll
        for (int i = 0; i < 4; ++i) {
            const int idx = i * 512 + tid;                 // 0..2047
            const int row = idx >> 3;                      // 0..255
            const int col = ((idx & 7) * 16) ^ ((row & 7) << 4);
            gload_lds16(Aq + (size_t)(m0 + row) * K + kt + col,
                        &As[b][0] + idx * 16);
        }
    };

    // prologue: A tile 0
    stage(0, 0);
    asm volatile("s_waitcnt vmcnt(0)" ::: "memory");
    __builtin_amdgcn_s_barrier();

    for (int t = 0; t < nkt; ++t) {
        const int cur = t & 1;
        const uint8_t* pa = &As[cur][0] + (wm * 128 + lr) * BKB;

        // ---- issue B(t): 8 coalesced global dwordx4 -> regs ----
        i32x8 bv[4];
#pragma unroll
        for (int ni = 0; ni < 4; ni++) {
            const uint8_t* p = bbase + ((size_t)ni * nkt + t) * 2048;
            i32x4 lo = *(const i32x4*)p;
            i32x4 hi = *(const i32x4*)(p + 16);
            bv[ni] = __builtin_shufflevector(lo, hi, 0, 1, 2, 3, 4, 5, 6, 7);
        }
        __builtin_amdgcn_sched_barrier(0);

        // ---- issue A frags 0..3 (8 b128), then next-tile staging ----
        i32x8 a0 = read_frag(pa,            off0, off1);
        i32x8 a1 = read_frag(pa + 16 * BKB, off0, off1);
        i32x8 a2 = read_frag(pa + 32 * BKB, off0, off1);
        i32x8 a3 = read_frag(pa + 48 * BKB, off0, off1);
        __builtin_amdgcn_sched_barrier(0);
        const bool pre = (t + 1 < nkt);
        if (pre) stage(cur ^ 1, (t + 1) * BKB);
        __builtin_amdgcn_sched_barrier(0);

        // ---- g0: B ready (stage's 4 vmem may stay in flight), a0,a1 ready --
        if (pre) asm volatile("s_waitcnt vmcnt(4)" ::: "memory");
        else     asm volatile("s_waitcnt vmcnt(0)" ::: "memory");
        WAIT_LGKM(4);
        __builtin_amdgcn_s_setprio(1);
#pragma unroll
        for (int ni = 0; ni < 4; ni++) {
            acc[0][ni] = MFMA_MX(a0, bv[ni], acc[0][ni]);
            acc[1][ni] = MFMA_MX(a1, bv[ni], acc[1][ni]);
        }
        __builtin_amdgcn_s_setprio(0);

        // ---- g1: issue pair2, wait pair1 ----
        i32x8 a4 = read_frag(pa + 64 * BKB, off0, off1);
        i32x8 a5 = read_frag(pa + 80 * BKB, off0, off1);
        WAIT_LGKM(4);
        __builtin_amdgcn_s_setprio(1);
#pragma unroll
        for (int ni = 0; ni < 4; ni++) {
            acc[2][ni] = MFMA_MX(a2, bv[ni], acc[2][ni]);
            acc[3][ni] = MFMA_MX(a3, bv[ni], acc[3][ni]);
        }
        __builtin_amdgcn_s_setprio(0);

        // ---- g2: issue pair3, wait pair2 ----
        i32x8 a6 = read_frag(pa + 96 * BKB,  off0, off1);
        i32x8 a7 = read_frag(pa + 112 * BKB, off0, off1);
        WAIT_LGKM(4);
        __builtin_amdgcn_s_setprio(1);
#pragma unroll
        for (int ni = 0; ni < 4; ni++) {
            acc[4][ni] = MFMA_MX(a4, bv[ni], acc[4][ni]);
            acc[5][ni] = MFMA_MX(a5, bv[ni], acc[5][ni]);
        }
        __builtin_amdgcn_s_setprio(0);

        // ---- g3: wait pair3 (all tile-t LDS reads retired after this) ----
        WAIT_LGKM(0);
        __builtin_amdgcn_s_setprio(1);
#pragma unroll
        for (int ni = 0; ni < 4; ni++) {
            acc[6][ni] = MFMA_MX(a6, bv[ni], acc[6][ni]);
            acc[7][ni] = MFMA_MX(a7, bv[ni], acc[7][ni]);
        }
        __builtin_amdgcn_s_setprio(0);

        // ---- end of iter: A tile t+1 fully in LDS before next top ----
        asm volatile("s_waitcnt vmcnt(0)" ::: "memory");
        __builtin_amdgcn_sched_barrier(0);
        __builtin_amdgcn_s_barrier();
    }

    // ---- epilogue: dequant + bias (C/D: col=lane&15, row=(lane>>4)*4+j) ----
    const float is = isp[0];
#pragma unroll
    for (int ni = 0; ni < 4; ni++) {
        const int cidx = n0 + wn * 64 + ni * 16 + lr;
        const float sc = is * wsc[cidx / ocPerChunk];
        const float bs = bias[cidx];
#pragma unroll
        for (int mi = 0; mi < 8; mi++) {
            const int rbase = m0 + wm * 128 + mi * 16 + (lane >> 4) * 4;
#pragma unroll
            for (int j = 0; j < 4; j++)
                out[(size_t)(rbase + j) * N + cidx] = acc[mi][ni][j] * sc + bs;
        }
    }
}

// ---------------------------------------------------------------------------
extern "C" void kernel_launch(void* const* d_in, const int* in_sizes, int n_in,
                              void* d_out, int out_size, void* d_ws, size_t ws_size,
                              hipStream_t stream) {
    const float* x        = (const float*)d_in[0];
    const float* w        = (const float*)d_in[1];
    const float* bias     = (const float*)d_in[2];
    const float* in_scale = (const float*)d_in[3];
    const float* w_scales = (const float*)d_in[4];
    float* out = (float*)d_out;

    const int N = in_sizes[2];               // 4096
    const int K = in_sizes[1] / N;           // 4096
    const int M = in_sizes[0] / K;           // 16384
    const int CHUNKS = in_sizes[4];          // 4
    const int ocPerChunk = N / CHUNKS;       // 1024

    uint8_t* xq = (uint8_t*)d_ws;            // M*K bytes
    uint8_t* wq = xq + (size_t)M * K;        // N*K bytes (fragment-shuffled)

    const int xn16 = (int)(((size_t)M * K) / 16);

    quant_x_kernel<<<2048, 256, 0, stream>>>(x, in_scale, (uint4*)xq, xn16);
    quant_w_kernel<<<2048, 256, 0, stream>>>(w, w_scales, wq, N, K, ocPerChunk);

    const int nblk = (M / BM) * (N / BN);    // 64 * 16 = 1024
    gemm_fp8_kernel<<<dim3(nblk), 512, 0, stream>>>(xq, wq, bias, in_scale,
                                                    w_scales, out, M, N, K,
                                                    ocPerChunk);
}